// Round 9
// baseline (439.238 us; speedup 1.0000x reference)
//
#include <hip/hip_runtime.h>
#include <hip/hip_cooperative_groups.h>
#include <math.h>

namespace cg = cooperative_groups;

#define D 512
#define M 128
#define B 16
#define KSEL 4
#define NC 2048           // M*B
#define NTOK 4096         // 2*2048

typedef unsigned short ushort;
typedef unsigned int uint;
typedef unsigned long long u64;
typedef __attribute__((ext_vector_type(8))) short short8;   // 8 bf16 (4 VGPRs)
typedef __attribute__((ext_vector_type(4))) float floatx4;  // 4 fp32 acc

// ws layout (float indices)
#define WS_EACC   0       // [128]  (written directly by listbuild phase)
#define WS_CACC   128     // [128]
#define WS_VSUM   256     // [1]
#define WS_USUM   257     // [1]
#define WS_CNT_I  258     // int counts [128]
#define WS_VSCALE 512     // [2048] 1/||V col||
#define WS_USCALE 2560    // [2048] tanh(us)/||U col||
#define WS_E_F    4608    // energies: chunked [32][NTOK][4] fp32 (2 MB, dense writes)
#define WS_RBF_F  528896  // R bf16 [NTOK][NC] (16 MB)
#define WS_XH_F   2626048 // xh bf16 [NTOK][D]; REUSED as contrib after gram
#define WS_XL_F   3674624 // xl bf16
#define WS_VHT_F  4723200 // VhT bf16 [NC][D]
#define WS_VLT_F  5247488
#define WS_UHT_F  5771776 // UhT bf16 [NC][D] (col = m*16+b)
#define WS_ULT_F  6296064 // (dead; slot kept for layout)
#define WS_LIST_F 6820352 // int [128][4096] per-expert token lists, packed (t<<2)|k
#define WS_SEL_F  7344640 // u64 [NTOK*KSEL] dense selections (128 KB, atomic-free)
                          // end: 7377408 floats = 29.5 MB

// out layout (floats)
#define OUT_TE   2097152
#define OUT_EPE  2097153
#define OUT_RE   2097281
#define OUT_SR   2097409
#define OUT_VPEN 2097537
#define OUT_UPEN 2097538
#define OUT_AUX  2097539

#define GLDS16(g, l) __builtin_amdgcn_global_load_lds(                        \
    (const __attribute__((address_space(1))) unsigned int*)(g),               \
    (__attribute__((address_space(3))) unsigned int*)(l), 16, 0, 0)

__device__ __forceinline__ ushort f2bf(float f) {   // RNE
    union { float f; uint u; } a; a.f = f;
    uint u = a.u;
    u += 0x7fffu + ((u >> 16) & 1u);
    return (ushort)(u >> 16);
}
__device__ __forceinline__ float bf2f(ushort h) {
    union { uint u; float f; } a; a.u = ((uint)h) << 16;
    return a.f;
}

// ---------------- fused prep: converts + scales + ws-zero (1570 blocks) ----
__launch_bounds__(256)
__global__ void prep_kernel(const float* __restrict__ x, const float* __restrict__ V,
                            const float* __restrict__ U, const float* __restrict__ us_in,
                            ushort* __restrict__ xh, ushort* __restrict__ xl,
                            ushort* __restrict__ vht, ushort* __restrict__ vlt,
                            ushort* __restrict__ uht,
                            float* __restrict__ ws) {
    __shared__ float ts[64][65];
    const int bid = blockIdx.x;
    const int tid = threadIdx.x;

    if (bid < 1024) {                       // convert_x
        const int idx = (bid * 256 + tid) * 8;
        float4 v0 = *(const float4*)(x + idx);
        float4 v1 = *(const float4*)(x + idx + 4);
        float vv[8] = {v0.x, v0.y, v0.z, v0.w, v1.x, v1.y, v1.z, v1.w};
        union { ushort u[8]; uint4 q; } H, L;
#pragma unroll
        for (int j = 0; j < 8; ++j) {
            ushort h = f2bf(vv[j]);
            H.u[j] = h;
            L.u[j] = f2bf(vv[j] - bf2f(h));
        }
        *(uint4*)(xh + idx) = H.q;
        *(uint4*)(xl + idx) = L.q;
    } else if (bid < 1280) {                // convert_VT (64x64 tile transpose)
        const int vb = bid - 1024;
        const int col0 = (vb & 31) * 64;
        const int d0 = (vb >> 5) * 64;
#pragma unroll
        for (int i = 0; i < 16; ++i) {
            int idx = i * 256 + tid;
            int r = idx >> 6, c = idx & 63;
            ts[r][c] = V[(size_t)(d0 + r) * NC + col0 + c];
        }
        __syncthreads();
#pragma unroll
        for (int i = 0; i < 16; ++i) {
            int idx = i * 256 + tid;
            int c2 = idx >> 6, d2 = idx & 63;
            float v = ts[d2][c2];
            ushort h = f2bf(v);
            vht[(size_t)(col0 + c2) * D + d0 + d2] = h;
            vlt[(size_t)(col0 + c2) * D + d0 + d2] = f2bf(v - bf2f(h));
        }
    } else if (bid < 1408) {                // convert_UT (one expert per block)
        const int m = bid - 1280;
        float (*t2)[129] = (float (*)[129])ts;   // 16 x 129 view
        for (int d0 = 0; d0 < D; d0 += 128) {
            __syncthreads();
#pragma unroll
            for (int i = 0; i < 8; ++i) {
                int idx = i * 256 + tid;
                int d2 = idx >> 4, b2 = idx & 15;
                t2[b2][d2] = U[(size_t)m * (D * B) + (size_t)(d0 + d2) * B + b2];
            }
            __syncthreads();
#pragma unroll
            for (int i = 0; i < 8; ++i) {
                int idx = i * 256 + tid;
                int b3 = idx >> 7, d3 = idx & 127;
                uht[(size_t)((m << 4) + b3) * D + d0 + d3] = f2bf(t2[b3][d3]);
            }
        }
    } else {                                // scales + ws-head zero
        const int bx = bid - 1408;
        if (bx >= 160) {
            ws[(bx - 160) * 256 + tid] = 0.0f;
            return;
        }
        if (bx < 32) {
            const int c = bx * 64 + (tid & 63);
            const int dg = tid >> 6;
            float s = 0.0f;
            for (int d = dg; d < D; d += 4) {
                float v = V[(size_t)d * NC + c];
                s = fmaf(v, v, s);
            }
            float (*sh)[64] = (float (*)[64])ts;
            sh[dg][tid & 63] = s;
            __syncthreads();
            if (tid < 64) {
                float t = (sh[0][tid] + sh[1][tid]) + (sh[2][tid] + sh[3][tid]);
                ws[WS_VSCALE + bx * 64 + tid] = 1.0f / sqrtf(t);
            }
        } else {
            const int m = bx - 32;
            const float* p = U + (size_t)m * (D * B);
            float s = 0.0f;
            for (int i = tid; i < D * B; i += 256) {
                float v = p[i];
                s = fmaf(v, v, s);
            }
            float* sh2 = &ts[0][0];
            sh2[tid] = s;
            __syncthreads();
            if (tid < 16) {
                float t = 0.0f;
#pragma unroll
                for (int j = 0; j < 16; ++j) t += sh2[tid + (j << 4)];
                ws[WS_USCALE + (m << 4) + tid] = tanhf(us_in[(m << 4) + tid]) / sqrtf(t);
            }
        }
    }
}

// ---------------- fused MFMA: gemm tiles (blocks 0..511) + gram tiles (512..783)
// ROUND-6 VERBATIM (proven 43-44us / MfmaUtil 26% twice): 2-barrier GLDS
// structure for BOTH paths (gram stages hi tiles only) + XCD swizzle + dense
// E2 writes. 4x-confirmed law: MFMA operands must come through the
// GLDS+barrier cadence.
__launch_bounds__(256)
__global__ void mfma_fused(const ushort* __restrict__ xh, const ushort* __restrict__ xl,
                           const ushort* __restrict__ vht, const ushort* __restrict__ vlt,
                           const ushort* __restrict__ uht,
                           float* __restrict__ ws, ushort* __restrict__ rbf) {
    __shared__ ushort smem[16384];   // 1 buf x 4 tiles x (128 rows x 32 bf16)
    const int bid = blockIdx.x;
    const int tid = threadIdx.x, lane = tid & 63, w = tid >> 6;
    const int wr = w >> 1, wc = w & 1;
    const int r15 = lane & 15, q = lane >> 4;
    const int srl = lane >> 2;
    const int skq = (lane & 3) ^ ((lane >> 3) & 3);
    const int perm8 = (q ^ ((r15 >> 1) & 3)) * 8;

    const int is_gemm = bid < 512;
    const ushort* srcs[4];
    int rbase[4];
    int gi = 0, gj = 0, which = 0;
    if (is_gemm) {
        // XCD tile swizzle: xcd = bid&7 owns tokSeg = xcd>>1, colSeg = xcd&1
        const int x = bid & 7, inner = bid >> 3;
        const int tokG = ((x >> 1) << 3) + (inner & 7);   // 0..31
        const int colG = ((x & 1) << 3) + (inner >> 3);   // 0..15
        const int tokB = tokG * 128, colB = colG * 128;
        srcs[0] = xh; srcs[1] = xl; srcs[2] = vht; srcs[3] = vlt;
        rbase[0] = tokB; rbase[1] = tokB; rbase[2] = colB; rbase[3] = colB;
    } else {
        int t = bid - 512;
        which = t >= 136;
        if (which) t -= 136;
        int bi = 0, rem = 16;
        while (t >= rem) { t -= rem; --rem; ++bi; }
        gi = bi; gj = bi + t;
        const ushort* ht = which ? uht : vht;
        srcs[0] = ht; srcs[1] = ht; srcs[2] = ht; srcs[3] = ht;
        rbase[0] = gi * 128; rbase[1] = gi * 128; rbase[2] = gj * 128; rbase[3] = gj * 128;
    }

    floatx4 acc[4][4];
#pragma unroll
    for (int i = 0; i < 4; ++i)
#pragma unroll
        for (int j = 0; j < 4; ++j) acc[i][j] = (floatx4){0.f, 0.f, 0.f, 0.f};

    auto stage = [&](int c) {
        const int kb = c * 32 + skq * 8;
#pragma unroll
        for (int tI = 0; tI < 4; ++tI) {
            if (!is_gemm && (tI & 1)) continue;    // gram: hi tiles only
            const ushort* s = srcs[tI] + (size_t)rbase[tI] * D + kb;
#pragma unroll
            for (int sub = 0; sub < 2; ++sub) {
                const int row16 = w * 32 + sub * 16;
                GLDS16(s + (size_t)(row16 + srl) * D,
                       &smem[tI * 4096 + row16 * 32]);
            }
        }
    };

    stage(0);
    for (int c = 0; c < 16; ++c) {
        __syncthreads();                 // A: buffer staged (vmcnt drained), prior reads done
        short8 ah[4], al[4], bh[4], bl[4];
#pragma unroll
        for (int s = 0; s < 4; ++s) {
            const int ra = (wr * 64 + s * 16 + r15) * 32 + perm8;
            ah[s] = *(const short8*)&smem[ra];
            const int rb = (wc * 64 + s * 16 + r15) * 32 + perm8;
            bh[s] = *(const short8*)&smem[8192 + rb];
            if (is_gemm) {
                al[s] = *(const short8*)&smem[4096 + ra];
                bl[s] = *(const short8*)&smem[12288 + rb];
            }
        }
        __syncthreads();                 // B: lgkm drained -> reads landed in regs
        if (c < 15) stage(c + 1);        // overwrite same buffer; overlaps MFMAs below
#pragma unroll
        for (int st = 0; st < 4; ++st)
#pragma unroll
            for (int sc = 0; sc < 4; ++sc) {
                acc[st][sc] = __builtin_amdgcn_mfma_f32_16x16x32_bf16(ah[st], bh[sc], acc[st][sc], 0, 0, 0);
                if (is_gemm) {           // per-acc order hh->hl->lh == round-0 numerics
                    acc[st][sc] = __builtin_amdgcn_mfma_f32_16x16x32_bf16(ah[st], bl[sc], acc[st][sc], 0, 0, 0);
                    acc[st][sc] = __builtin_amdgcn_mfma_f32_16x16x32_bf16(al[st], bh[sc], acc[st][sc], 0, 0, 0);
                }
            }
    }

    if (is_gemm) {
        const int tok0 = rbase[0] + wr * 64, col0 = rbase[2] + wc * 64;
        const int cg4 = col0 >> 6;                    // 64-col chunk (4 experts)
        float* e2base = ws + WS_E_F + (size_t)cg4 * (NTOK * 4);
#pragma unroll
        for (int st = 0; st < 4; ++st) {
            const int rowb = tok0 + st * 16 + q * 4;
            float er[4][4];
#pragma unroll
            for (int sc = 0; sc < 4; ++sc) {
                const int colg = col0 + sc * 16 + r15;
                const float vs = ws[WS_VSCALE + colg];
                float r0 = acc[st][sc][0] * vs;
                float r1 = acc[st][sc][1] * vs;
                float r2 = acc[st][sc][2] * vs;
                float r3 = acc[st][sc][3] * vs;
                rbf[(size_t)(rowb + 0) * NC + colg] = f2bf(r0);
                rbf[(size_t)(rowb + 1) * NC + colg] = f2bf(r1);
                rbf[(size_t)(rowb + 2) * NC + colg] = f2bf(r2);
                rbf[(size_t)(rowb + 3) * NC + colg] = f2bf(r3);
                float e0 = r0 * r0, e1 = r1 * r1, e2 = r2 * r2, e3 = r3 * r3;
#pragma unroll
                for (int mk = 1; mk < 16; mk <<= 1) {
                    e0 += __shfl_xor(e0, mk);
                    e1 += __shfl_xor(e1, mk);
                    e2 += __shfl_xor(e2, mk);
                    e3 += __shfl_xor(e3, mk);
                }
                er[sc][0] = e0; er[sc][1] = e1; er[sc][2] = e2; er[sc][3] = e3;
            }
            if (r15 == 0) {                           // dense 16B per token, full lines
#pragma unroll
                for (int j = 0; j < 4; ++j) {
                    *(float4*)(e2base + (size_t)(rowb + j) * 4) =
                        make_float4(er[0][j], er[1][j], er[2][j], er[3][j]);
                }
            }
        }
    } else {
        const float* scl = ws + (which ? WS_USCALE : WS_VSCALE);
        float* sum_out = ws + (which ? WS_USUM : WS_VSUM);
        float local = 0.0f;
#pragma unroll
        for (int sc = 0; sc < 4; ++sc) {
            const int colg = gj * 128 + wc * 64 + sc * 16 + r15;
            const float scj = scl[colg];
#pragma unroll
            for (int st = 0; st < 4; ++st) {
#pragma unroll
                for (int reg = 0; reg < 4; ++reg) {
                    const int rowg = gi * 128 + wr * 64 + st * 16 + q * 4 + reg;
                    float g = acc[st][sc][reg] * scl[rowg] * scj;
                    if (rowg == colg) g -= 1.0f;
                    local += fabsf(g);
                }
            }
        }
        if (gi < gj) local *= 2.0f;
#pragma unroll
        for (int mk = 1; mk < 64; mk <<= 1) local += __shfl_xor(local, mk);
        __shared__ float red[4];
        if (lane == 0) red[w] = local;
        __syncthreads();
        if (tid == 0) atomicAdd(sum_out, (red[0] + red[1]) + (red[2] + red[3]));
    }
}

// ---------------- cooperative tail: topk -> listbuild -> contrib -> combine
// One launch, 3 grid.sync()s replacing 3 kernel boundaries. Phase bodies are
// byte-identical to the round-8 kernels (proven); early-returns converted to
// guards so every thread reaches every sync. 1024 blocks x 256 = 4 blocks/CU
// co-resident (launch_bounds caps VGPR at 128; phases use ~80).
__launch_bounds__(256, 4)
__global__ void tail_kernel(const float* __restrict__ x, const float* __restrict__ U,
                            const ushort* __restrict__ rbf, float* __restrict__ ws,
                            uint* __restrict__ contrib, float* __restrict__ out) {
    cg::grid_group grid = cg::this_grid();
    const int bid = blockIdx.x;
    const int tid = threadIdx.x, lane = tid & 63, w = tid >> 6;

    __shared__ int sc_[256];
    __shared__ float sv[256];
    __shared__ float sh2[2];

    // ======== P1: wave-per-token top-4 (exact round-8 topk) ========
    {
        const int t = bid * 4 + w;
        const int cg4 = lane >> 1;
        const int e2off = (lane & 1) * 2;
        const float2 ev = *(const float2*)(ws + WS_E_F +
                                           ((size_t)cg4 * NTOK + t) * 4 + e2off);
        const uint i0 = (uint)(lane * 2), i1 = i0 + 1;
        u64 k0 = ((u64)__float_as_uint(ev.x) << 32) | (uint)(~i0);
        u64 k1 = ((u64)__float_as_uint(ev.y) << 32) | (uint)(~i1);
        u64 s0 = k0 > k1 ? k0 : k1;
        u64 s1 = k0 > k1 ? k1 : k0;
        u64 s2 = 0, s3 = 0;

#pragma unroll
        for (int mk = 1; mk < 64; mk <<= 1) {
            u64 o0 = __shfl_xor(s0, mk);
            u64 o1 = __shfl_xor(s1, mk);
            u64 o2 = __shfl_xor(s2, mk);
            u64 o3 = __shfl_xor(s3, mk);
            u64 c0 = s0 > o3 ? s0 : o3;
            u64 c1 = s1 > o2 ? s1 : o2;
            u64 c2 = s2 > o1 ? s2 : o1;
            u64 c3 = s3 > o0 ? s3 : o0;
            u64 d0 = c0 > c2 ? c0 : c2, d2 = c0 > c2 ? c2 : c0;
            u64 d1 = c1 > c3 ? c1 : c3, d3 = c1 > c3 ? c3 : c1;
            s0 = d0 > d1 ? d0 : d1; s1 = d0 > d1 ? d1 : d0;
            s2 = d2 > d3 ? d2 : d3; s3 = d2 > d3 ? d3 : d2;
        }

        if (lane < 4) {
            u64 key = (lane == 0) ? s0 : (lane == 1) ? s1 : (lane == 2) ? s2 : s3;
            const uint e = (uint)(~(uint)key) & 127u;     // expert index
            const u64 lo = ((u64)(e << 14)) | (u64)((t << 2) | lane);
            ((u64*)(ws + WS_SEL_F))[(t << 2) + lane] =
                (key & 0xFFFFFFFF00000000ull) | lo;
        }
    }
    grid.sync();

    // ======== P2: listbuild (blocks 0..127, exact round-8 body) ========
    if (bid < M) {
        const int e = bid;
        const u64* sels = (const u64*)(ws + WS_SEL_F);
        int* icnt = (int*)ws + WS_CNT_I;
        int* ilist = (int*)(ws + WS_LIST_F) + (e << 12);

        const int base_idx = tid * 64;
        int cnt = 0;
        float vsum = 0.0f;
#pragma unroll 8
        for (int j = 0; j < 64; ++j) {
            u64 s = sels[base_idx + j];
            if ((int)((s >> 14) & 127u) == e) {
                ++cnt;
                vsum += __uint_as_float((uint)(s >> 32));
            }
        }
        sc_[tid] = cnt;
        sv[tid] = vsum;
        __syncthreads();

#pragma unroll
        for (int off = 1; off < 256; off <<= 1) {
            int v = (tid >= off) ? sc_[tid - off] : 0;
            __syncthreads();
            sc_[tid] += v;
            __syncthreads();
        }
        const int wbase = sc_[tid] - cnt;
        const int total = sc_[255];

        if (cnt > 0) {
            int p = wbase;
#pragma unroll 8
            for (int j = 0; j < 64; ++j) {
                u64 s = sels[base_idx + j];
                if ((int)((s >> 14) & 127u) == e)
                    ilist[p++] = (int)(s & 0x3FFFu);   // (t<<2)|k
            }
        }

#pragma unroll
        for (int off = 128; off > 0; off >>= 1) {
            __syncthreads();
            if (tid < off) sv[tid] += sv[tid + off];
        }
        if (tid == 0) {
            icnt[e] = total;
            ws[WS_EACC + e] = sv[0];
            ws[WS_CACC + e] = (float)total;
        }
    }
    grid.sync();

    // ======== P3: expert contributions (e = bid&127, y = bid>>7; y-step 8) ====
    {
        const int e = bid & 127;
        const int y = bid >> 7;
        const int cnt = ((const int*)ws)[WS_CNT_I + e];
        if (y < cnt) {
            float usc[16];
#pragma unroll
            for (int b = 0; b < 16; ++b) usc[b] = ws[WS_USCALE + (e << 4) + b];

            const float* Up = U + (size_t)e * (D * B);
            float u0[16], u1[16];
#pragma unroll
            for (int qd = 0; qd < 4; ++qd) {
                float4 a = *(const float4*)(Up + (size_t)(2 * tid) * B + qd * 4);
                float4 b4 = *(const float4*)(Up + (size_t)(2 * tid + 1) * B + qd * 4);
                u0[qd * 4 + 0] = a.x * usc[qd * 4 + 0];
                u0[qd * 4 + 1] = a.y * usc[qd * 4 + 1];
                u0[qd * 4 + 2] = a.z * usc[qd * 4 + 2];
                u0[qd * 4 + 3] = a.w * usc[qd * 4 + 3];
                u1[qd * 4 + 0] = b4.x * usc[qd * 4 + 0];
                u1[qd * 4 + 1] = b4.y * usc[qd * 4 + 1];
                u1[qd * 4 + 2] = b4.z * usc[qd * 4 + 2];
                u1[qd * 4 + 3] = b4.w * usc[qd * 4 + 3];
            }

            const int* ilist = (const int*)(ws + WS_LIST_F) + (e << 12);
            int i = y;
            int pk = ilist[i];
            while (i < cnt) {
                const int t = pk >> 2, k = pk & 3;
                const ushort* rp = rbf + (size_t)t * NC + (e << 4);
                union { ushort u[16]; uint4 q[2]; } R;
                R.q[0] = *(const uint4*)(rp);
                R.q[1] = *(const uint4*)(rp + 8);
                const int inext = i + 8;
                if (inext < cnt) pk = ilist[inext];
                float acc0 = 0.0f, acc1 = 0.0f;
#pragma unroll
                for (int b = 0; b < 16; ++b) {
                    const float wv = bf2f(R.u[b]);
                    acc0 = fmaf(u0[b], wv, acc0);
                    acc1 = fmaf(u1[b], wv, acc1);
                }
                contrib[(size_t)((t << 2) + k) * 256 + tid] =
                    (uint)f2bf(acc0) | ((uint)f2bf(acc1) << 16);
                i = inext;
            }
        }
    }
    grid.sync();

    // ======== P4: combine (+ finalize in block 0) ========
    if (bid == 0) {                        // finalize scalars (guarded, no returns)
        const int m = tid;
        float e = 0.0f, c = 0.0f;
        if (m < 128) {
            e = ws[WS_EACC + m] * (1.0f / (float)NTOK);
            c = ws[WS_CACC + m] * (1.0f / (float)NTOK);
        }
        float s = e;
#pragma unroll
        for (int off = 32; off > 0; off >>= 1) s += __shfl_down(s, off);
        if (m == 0) sh2[0] = s;
        if (m == 64) sh2[1] = s;
        __syncthreads();
        if (m < 128) {
            float total = sh2[0] + sh2[1];
            float total_energy = fmaxf(total, 1e-12f);
            out[OUT_EPE + m] = e;
            out[OUT_RE + m] = e / total_energy;
            out[OUT_SR + m] = c;
            if (m == 0) {
                out[OUT_TE] = total_energy;
                float inv_n2 = 1.0f / ((float)NC * (float)NC);
                float sqrtD = sqrtf((float)D);
                float vpen = ws[WS_VSUM] * inv_n2 * sqrtD;
                float upen = ws[WS_USUM] * inv_n2 * sqrtD;
                out[OUT_VPEN] = vpen;
                out[OUT_UPEN] = upen;
                out[OUT_AUX] = 0.01f * vpen - total_energy;
            }
        }
    }
    {
        const int gid = bid * 256 + tid;
        const int t = gid >> 6;
        const int dq = (gid & 63) << 3;
        const uint4* cp = (const uint4*)contrib;

        float s[8];
        float4 x0 = *(const float4*)(x + (size_t)t * D + dq);
        float4 x1 = *(const float4*)(x + (size_t)t * D + dq + 4);
        s[0] = x0.x; s[1] = x0.y; s[2] = x0.z; s[3] = x0.w;
        s[4] = x1.x; s[5] = x1.y; s[6] = x1.z; s[7] = x1.w;
#pragma unroll
        for (int k = 0; k < KSEL; ++k) {
            uint4 cvec = cp[(size_t)((t << 2) + k) * 64 + (dq >> 3)];
            uint cc[4] = {cvec.x, cvec.y, cvec.z, cvec.w};
#pragma unroll
            for (int j = 0; j < 4; ++j) {
                s[2 * j]     += bf2f((ushort)(cc[j] & 0xffffu));
                s[2 * j + 1] += bf2f((ushort)(cc[j] >> 16));
            }
        }
        float* op = out + (size_t)t * D + dq;
        *(float4*)(op)     = make_float4(s[0], s[1], s[2], s[3]);
        *(float4*)(op + 4) = make_float4(s[4], s[5], s[6], s[7]);
    }
}

extern "C" void kernel_launch(void* const* d_in, const int* in_sizes, int n_in,
                              void* d_out, int out_size, void* d_ws, size_t ws_size,
                              hipStream_t stream) {
    const float* x  = (const float*)d_in[0];
    const float* V  = (const float*)d_in[1];
    const float* U  = (const float*)d_in[2];
    const float* us = (const float*)d_in[3];
    float* out = (float*)d_out;
    float* ws  = (float*)d_ws;

    ushort* xh  = (ushort*)(ws + WS_XH_F);
    ushort* xl  = (ushort*)(ws + WS_XL_F);
    ushort* vht = (ushort*)(ws + WS_VHT_F);
    ushort* vlt = (ushort*)(ws + WS_VLT_F);
    ushort* uht = (ushort*)(ws + WS_UHT_F);
    ushort* rbf = (ushort*)(ws + WS_RBF_F);
    uint* contrib = (uint*)(ws + WS_XH_F);   // reuses xh..ult after mfma_fused

    prep_kernel<<<1570, 256, 0, stream>>>(x, V, U, us, xh, xl, vht, vlt, uht, ws);
    mfma_fused<<<784, 256, 0, stream>>>(xh, xl, vht, vlt, uht, ws, rbf);

    const ushort* rbf_c = rbf;
    void* args[] = {(void*)&x, (void*)&U, (void*)&rbf_c, (void*)&ws,
                    (void*)&contrib, (void*)&out};
    hipLaunchCooperativeKernel((void*)tail_kernel, dim3(1024), dim3(256),
                               args, 0, stream);
}

// Round 10
// 167.393 us; speedup vs baseline: 2.6240x; 2.6240x over previous
//
#include <hip/hip_runtime.h>
#include <math.h>

#define D 512
#define M 128
#define B 16
#define KSEL 4
#define NC 2048           // M*B
#define NTOK 4096         // 2*2048

typedef unsigned short ushort;
typedef unsigned int uint;
typedef unsigned long long u64;
typedef __attribute__((ext_vector_type(8))) short short8;   // 8 bf16 (4 VGPRs)
typedef __attribute__((ext_vector_type(4))) float floatx4;  // 4 fp32 acc

// ws layout (float indices)
#define WS_EACC   0       // [128]  (written directly by listbuild)
#define WS_CACC   128     // [128]
#define WS_VSUM   256     // [1]
#define WS_USUM   257     // [1]
#define WS_CNT_I  258     // int counts [128]
#define WS_VSCALE 512     // [2048] 1/||V col||
#define WS_USCALE 2560    // [2048] tanh(us)/||U col||
#define WS_E_F    4608    // energies: chunked [32][NTOK][4] fp32 (2 MB, dense writes)
#define WS_RBF_F  528896  // R bf16 [NTOK][NC] (16 MB)
#define WS_XH_F   2626048 // xh bf16 [NTOK][D]; REUSED as contrib after gram
#define WS_XL_F   3674624 // xl bf16
#define WS_VHT_F  4723200 // VhT bf16 [NC][D]
#define WS_VLT_F  5247488
#define WS_UHT_F  5771776 // UhT bf16 [NC][D] (col = m*16+b)
#define WS_ULT_F  6296064 // (dead; slot kept for layout)
#define WS_LIST_F 6820352 // int [128][4096] per-expert token lists, packed (t<<2)|k
#define WS_SEL_F  7344640 // u64 [NTOK*KSEL] dense selections (128 KB, atomic-free)
                          // end: 7377408 floats = 29.5 MB

// out layout (floats)
#define OUT_TE   2097152
#define OUT_EPE  2097153
#define OUT_RE   2097281
#define OUT_SR   2097409
#define OUT_VPEN 2097537
#define OUT_UPEN 2097538
#define OUT_AUX  2097539

#define GLDS16(g, l) __builtin_amdgcn_global_load_lds(                        \
    (const __attribute__((address_space(1))) unsigned int*)(g),               \
    (__attribute__((address_space(3))) unsigned int*)(l), 16, 0, 0)

__device__ __forceinline__ ushort f2bf(float f) {   // RNE
    union { float f; uint u; } a; a.f = f;
    uint u = a.u;
    u += 0x7fffu + ((u >> 16) & 1u);
    return (ushort)(u >> 16);
}
__device__ __forceinline__ float bf2f(ushort h) {
    union { uint u; float f; } a; a.u = ((uint)h) << 16;
    return a.f;
}

// ---------------- fused prep: converts + scales + ws-zero (1570 blocks) ----
// blocks [0,1024): convert_x ; [1024,1280): convert_VT ; [1280,1408): convert_UT ;
// [1408,1570): scales (incl. ws-head zero at 1568/1569)
__launch_bounds__(256)
__global__ void prep_kernel(const float* __restrict__ x, const float* __restrict__ V,
                            const float* __restrict__ U, const float* __restrict__ us_in,
                            ushort* __restrict__ xh, ushort* __restrict__ xl,
                            ushort* __restrict__ vht, ushort* __restrict__ vlt,
                            ushort* __restrict__ uht,
                            float* __restrict__ ws) {
    __shared__ float ts[64][65];
    const int bid = blockIdx.x;
    const int tid = threadIdx.x;

    if (bid < 1024) {                       // convert_x
        const int idx = (bid * 256 + tid) * 8;
        float4 v0 = *(const float4*)(x + idx);
        float4 v1 = *(const float4*)(x + idx + 4);
        float vv[8] = {v0.x, v0.y, v0.z, v0.w, v1.x, v1.y, v1.z, v1.w};
        union { ushort u[8]; uint4 q; } H, L;
#pragma unroll
        for (int j = 0; j < 8; ++j) {
            ushort h = f2bf(vv[j]);
            H.u[j] = h;
            L.u[j] = f2bf(vv[j] - bf2f(h));
        }
        *(uint4*)(xh + idx) = H.q;
        *(uint4*)(xl + idx) = L.q;
    } else if (bid < 1280) {                // convert_VT (64x64 tile transpose)
        const int vb = bid - 1024;
        const int col0 = (vb & 31) * 64;
        const int d0 = (vb >> 5) * 64;
#pragma unroll
        for (int i = 0; i < 16; ++i) {
            int idx = i * 256 + tid;
            int r = idx >> 6, c = idx & 63;
            ts[r][c] = V[(size_t)(d0 + r) * NC + col0 + c];
        }
        __syncthreads();
#pragma unroll
        for (int i = 0; i < 16; ++i) {
            int idx = i * 256 + tid;
            int c2 = idx >> 6, d2 = idx & 63;
            float v = ts[d2][c2];
            ushort h = f2bf(v);
            vht[(size_t)(col0 + c2) * D + d0 + d2] = h;
            vlt[(size_t)(col0 + c2) * D + d0 + d2] = f2bf(v - bf2f(h));
        }
    } else if (bid < 1408) {                // convert_UT (one expert per block)
        const int m = bid - 1280;
        float (*t2)[129] = (float (*)[129])ts;   // 16 x 129 view
        for (int d0 = 0; d0 < D; d0 += 128) {
            __syncthreads();
#pragma unroll
            for (int i = 0; i < 8; ++i) {
                int idx = i * 256 + tid;
                int d2 = idx >> 4, b2 = idx & 15;
                t2[b2][d2] = U[(size_t)m * (D * B) + (size_t)(d0 + d2) * B + b2];
            }
            __syncthreads();
#pragma unroll
            for (int i = 0; i < 8; ++i) {
                int idx = i * 256 + tid;
                int b3 = idx >> 7, d3 = idx & 127;
                uht[(size_t)((m << 4) + b3) * D + d0 + d3] = f2bf(t2[b3][d3]);
            }
        }
    } else {                                // scales + ws-head zero
        const int bx = bid - 1408;
        if (bx >= 160) {
            ws[(bx - 160) * 256 + tid] = 0.0f;
            return;
        }
        if (bx < 32) {
            const int c = bx * 64 + (tid & 63);
            const int dg = tid >> 6;
            float s = 0.0f;
            for (int d = dg; d < D; d += 4) {
                float v = V[(size_t)d * NC + c];
                s = fmaf(v, v, s);
            }
            float (*sh)[64] = (float (*)[64])ts;
            sh[dg][tid & 63] = s;
            __syncthreads();
            if (tid < 64) {
                float t = (sh[0][tid] + sh[1][tid]) + (sh[2][tid] + sh[3][tid]);
                ws[WS_VSCALE + bx * 64 + tid] = 1.0f / sqrtf(t);
            }
        } else {
            const int m = bx - 32;
            const float* p = U + (size_t)m * (D * B);
            float s = 0.0f;
            for (int i = tid; i < D * B; i += 256) {
                float v = p[i];
                s = fmaf(v, v, s);
            }
            float* sh2 = &ts[0][0];
            sh2[tid] = s;
            __syncthreads();
            if (tid < 16) {
                float t = 0.0f;
#pragma unroll
                for (int j = 0; j < 16; ++j) t += sh2[tid + (j << 4)];
                ws[WS_USCALE + (m << 4) + tid] = tanhf(us_in[(m << 4) + tid]) / sqrtf(t);
            }
        }
    }
}

// ---------------- fused MFMA: gemm tiles (blocks 0..511) + gram tiles (512..783)
// ROUND-6 STRUCTURE (proven 43-44us / MfmaUtil 26% three times): 2-barrier
// GLDS cadence for BOTH paths (gram stages hi tiles only) + XCD swizzle +
// dense E2 writes. 4x-confirmed law: MFMA operands must come through the
// GLDS+barrier cadence. Round-9 lesson: grid.sync costs ~100us on 8-XCD —
// kernel boundaries are the cheap synchronization primitive here.
__launch_bounds__(256)
__global__ void mfma_fused(const ushort* __restrict__ xh, const ushort* __restrict__ xl,
                           const ushort* __restrict__ vht, const ushort* __restrict__ vlt,
                           const ushort* __restrict__ uht,
                           float* __restrict__ ws, ushort* __restrict__ rbf) {
    __shared__ ushort smem[16384];   // 1 buf x 4 tiles x (128 rows x 32 bf16)
    const int bid = blockIdx.x;
    const int tid = threadIdx.x, lane = tid & 63, w = tid >> 6;
    const int wr = w >> 1, wc = w & 1;
    const int r15 = lane & 15, q = lane >> 4;
    const int srl = lane >> 2;
    const int skq = (lane & 3) ^ ((lane >> 3) & 3);
    const int perm8 = (q ^ ((r15 >> 1) & 3)) * 8;

    const int is_gemm = bid < 512;
    const ushort* srcs[4];
    int rbase[4];
    int gi = 0, gj = 0, which = 0;
    if (is_gemm) {
        // XCD tile swizzle: xcd = bid&7 owns tokSeg = xcd>>1, colSeg = xcd&1
        const int x = bid & 7, inner = bid >> 3;
        const int tokG = ((x >> 1) << 3) + (inner & 7);   // 0..31
        const int colG = ((x & 1) << 3) + (inner >> 3);   // 0..15
        const int tokB = tokG * 128, colB = colG * 128;
        srcs[0] = xh; srcs[1] = xl; srcs[2] = vht; srcs[3] = vlt;
        rbase[0] = tokB; rbase[1] = tokB; rbase[2] = colB; rbase[3] = colB;
    } else {
        int t = bid - 512;
        which = t >= 136;
        if (which) t -= 136;
        int bi = 0, rem = 16;
        while (t >= rem) { t -= rem; --rem; ++bi; }
        gi = bi; gj = bi + t;
        const ushort* ht = which ? uht : vht;
        srcs[0] = ht; srcs[1] = ht; srcs[2] = ht; srcs[3] = ht;
        rbase[0] = gi * 128; rbase[1] = gi * 128; rbase[2] = gj * 128; rbase[3] = gj * 128;
    }

    floatx4 acc[4][4];
#pragma unroll
    for (int i = 0; i < 4; ++i)
#pragma unroll
        for (int j = 0; j < 4; ++j) acc[i][j] = (floatx4){0.f, 0.f, 0.f, 0.f};

    auto stage = [&](int c) {
        const int kb = c * 32 + skq * 8;
#pragma unroll
        for (int tI = 0; tI < 4; ++tI) {
            if (!is_gemm && (tI & 1)) continue;    // gram: hi tiles only
            const ushort* s = srcs[tI] + (size_t)rbase[tI] * D + kb;
#pragma unroll
            for (int sub = 0; sub < 2; ++sub) {
                const int row16 = w * 32 + sub * 16;
                GLDS16(s + (size_t)(row16 + srl) * D,
                       &smem[tI * 4096 + row16 * 32]);
            }
        }
    };

    stage(0);
    for (int c = 0; c < 16; ++c) {
        __syncthreads();                 // A: buffer staged (vmcnt drained), prior reads done
        short8 ah[4], al[4], bh[4], bl[4];
#pragma unroll
        for (int s = 0; s < 4; ++s) {
            const int ra = (wr * 64 + s * 16 + r15) * 32 + perm8;
            ah[s] = *(const short8*)&smem[ra];
            const int rb = (wc * 64 + s * 16 + r15) * 32 + perm8;
            bh[s] = *(const short8*)&smem[8192 + rb];
            if (is_gemm) {
                al[s] = *(const short8*)&smem[4096 + ra];
                bl[s] = *(const short8*)&smem[12288 + rb];
            }
        }
        __syncthreads();                 // B: lgkm drained -> reads landed in regs
        if (c < 15) stage(c + 1);        // overwrite same buffer; overlaps MFMAs below
#pragma unroll
        for (int st = 0; st < 4; ++st)
#pragma unroll
            for (int sc = 0; sc < 4; ++sc) {
                acc[st][sc] = __builtin_amdgcn_mfma_f32_16x16x32_bf16(ah[st], bh[sc], acc[st][sc], 0, 0, 0);
                if (is_gemm) {           // per-acc order hh->hl->lh == round-0 numerics
                    acc[st][sc] = __builtin_amdgcn_mfma_f32_16x16x32_bf16(ah[st], bl[sc], acc[st][sc], 0, 0, 0);
                    acc[st][sc] = __builtin_amdgcn_mfma_f32_16x16x32_bf16(al[st], bh[sc], acc[st][sc], 0, 0, 0);
                }
            }
    }

    if (is_gemm) {
        const int tok0 = rbase[0] + wr * 64, col0 = rbase[2] + wc * 64;
        const int cg4 = col0 >> 6;                    // 64-col chunk (4 experts)
        float* e2base = ws + WS_E_F + (size_t)cg4 * (NTOK * 4);
#pragma unroll
        for (int st = 0; st < 4; ++st) {
            const int rowb = tok0 + st * 16 + q * 4;
            float er[4][4];
#pragma unroll
            for (int sc = 0; sc < 4; ++sc) {
                const int colg = col0 + sc * 16 + r15;
                const float vs = ws[WS_VSCALE + colg];
                float r0 = acc[st][sc][0] * vs;
                float r1 = acc[st][sc][1] * vs;
                float r2 = acc[st][sc][2] * vs;
                float r3 = acc[st][sc][3] * vs;
                rbf[(size_t)(rowb + 0) * NC + colg] = f2bf(r0);
                rbf[(size_t)(rowb + 1) * NC + colg] = f2bf(r1);
                rbf[(size_t)(rowb + 2) * NC + colg] = f2bf(r2);
                rbf[(size_t)(rowb + 3) * NC + colg] = f2bf(r3);
                float e0 = r0 * r0, e1 = r1 * r1, e2 = r2 * r2, e3 = r3 * r3;
#pragma unroll
                for (int mk = 1; mk < 16; mk <<= 1) {
                    e0 += __shfl_xor(e0, mk);
                    e1 += __shfl_xor(e1, mk);
                    e2 += __shfl_xor(e2, mk);
                    e3 += __shfl_xor(e3, mk);
                }
                er[sc][0] = e0; er[sc][1] = e1; er[sc][2] = e2; er[sc][3] = e3;
            }
            if (r15 == 0) {                           // dense 16B per token, full lines
#pragma unroll
                for (int j = 0; j < 4; ++j) {
                    *(float4*)(e2base + (size_t)(rowb + j) * 4) =
                        make_float4(er[0][j], er[1][j], er[2][j], er[3][j]);
                }
            }
        }
    } else {
        const float* scl = ws + (which ? WS_USCALE : WS_VSCALE);
        float* sum_out = ws + (which ? WS_USUM : WS_VSUM);
        float local = 0.0f;
#pragma unroll
        for (int sc = 0; sc < 4; ++sc) {
            const int colg = gj * 128 + wc * 64 + sc * 16 + r15;
            const float scj = scl[colg];
#pragma unroll
            for (int st = 0; st < 4; ++st) {
#pragma unroll
                for (int reg = 0; reg < 4; ++reg) {
                    const int rowg = gi * 128 + wr * 64 + st * 16 + q * 4 + reg;
                    float g = acc[st][sc][reg] * scl[rowg] * scj;
                    if (rowg == colg) g -= 1.0f;
                    local += fabsf(g);
                }
            }
        }
        if (gi < gj) local *= 2.0f;
#pragma unroll
        for (int mk = 1; mk < 64; mk <<= 1) local += __shfl_xor(local, mk);
        __shared__ float red[4];
        if (lane == 0) red[w] = local;
        __syncthreads();
        if (tid == 0) atomicAdd(sum_out, (red[0] + red[1]) + (red[2] + red[3]));
    }
}

// Wave-per-token top-4 (butterfly). Bookkeeping ATOMIC-FREE:
// each selected lane writes one dense u64 (val_bits<<32)|(e<<14)|(t<<2)|k.
__launch_bounds__(256)
__global__ void topk_kernel(float* __restrict__ ws) {
    const int tid = threadIdx.x, lane = tid & 63, w = tid >> 6;
    const int t = blockIdx.x * 4 + w;

    const int cg4 = lane >> 1;
    const int e2off = (lane & 1) * 2;
    const float2 ev = *(const float2*)(ws + WS_E_F +
                                       ((size_t)cg4 * NTOK + t) * 4 + e2off);
    const uint i0 = (uint)(lane * 2), i1 = i0 + 1;
    u64 k0 = ((u64)__float_as_uint(ev.x) << 32) | (uint)(~i0);
    u64 k1 = ((u64)__float_as_uint(ev.y) << 32) | (uint)(~i1);
    u64 s0 = k0 > k1 ? k0 : k1;
    u64 s1 = k0 > k1 ? k1 : k0;
    u64 s2 = 0, s3 = 0;

#pragma unroll
    for (int mk = 1; mk < 64; mk <<= 1) {
        u64 o0 = __shfl_xor(s0, mk);
        u64 o1 = __shfl_xor(s1, mk);
        u64 o2 = __shfl_xor(s2, mk);
        u64 o3 = __shfl_xor(s3, mk);
        u64 c0 = s0 > o3 ? s0 : o3;
        u64 c1 = s1 > o2 ? s1 : o2;
        u64 c2 = s2 > o1 ? s2 : o1;
        u64 c3 = s3 > o0 ? s3 : o0;
        u64 d0 = c0 > c2 ? c0 : c2, d2 = c0 > c2 ? c2 : c0;
        u64 d1 = c1 > c3 ? c1 : c3, d3 = c1 > c3 ? c3 : c1;
        s0 = d0 > d1 ? d0 : d1; s1 = d0 > d1 ? d1 : d0;
        s2 = d2 > d3 ? d2 : d3; s3 = d2 > d3 ? d3 : d2;
    }

    if (lane < 4) {
        u64 key = (lane == 0) ? s0 : (lane == 1) ? s1 : (lane == 2) ? s2 : s3;
        const uint e = (uint)(~(uint)key) & 127u;     // expert index
        const u64 lo = ((u64)(e << 14)) | (u64)((t << 2) | lane);
        ((u64*)(ws + WS_SEL_F))[(t << 2) + lane] =
            (key & 0xFFFFFFFF00000000ull) | lo;
    }
}

// One block per expert: scan dense sels (L2-hot 128 KB), stable LDS
// prefix-scan compaction into ilist stripe; write icnt/EACC/CACC directly.
__launch_bounds__(256)
__global__ void listbuild_kernel(float* __restrict__ ws) {
    const int e = blockIdx.x;
    const int tid = threadIdx.x;
    const u64* sels = (const u64*)(ws + WS_SEL_F);
    int* icnt = (int*)ws + WS_CNT_I;
    int* ilist = (int*)(ws + WS_LIST_F) + (e << 12);

    __shared__ int sc_[256];
    __shared__ float sv[256];

    const int base_idx = tid * 64;
    int cnt = 0;
    float vsum = 0.0f;
#pragma unroll 8
    for (int j = 0; j < 64; ++j) {
        u64 s = sels[base_idx + j];
        if ((int)((s >> 14) & 127u) == e) {
            ++cnt;
            vsum += __uint_as_float((uint)(s >> 32));
        }
    }
    sc_[tid] = cnt;
    sv[tid] = vsum;
    __syncthreads();

#pragma unroll
    for (int off = 1; off < 256; off <<= 1) {
        int v = (tid >= off) ? sc_[tid - off] : 0;
        __syncthreads();
        sc_[tid] += v;
        __syncthreads();
    }
    const int wbase = sc_[tid] - cnt;
    const int total = sc_[255];

    if (cnt > 0) {
        int p = wbase;
#pragma unroll 8
        for (int j = 0; j < 64; ++j) {
            u64 s = sels[base_idx + j];
            if ((int)((s >> 14) & 127u) == e)
                ilist[p++] = (int)(s & 0x3FFFu);   // (t<<2)|k
        }
    }

#pragma unroll
    for (int off = 128; off > 0; off >>= 1) {
        __syncthreads();
        if (tid < off) sv[tid] += sv[tid + off];
    }
    if (tid == 0) {
        icnt[e] = total;
        ws[WS_EACC + e] = sv[0];
        ws[WS_CACC + e] = (float)total;
    }
}

// Expert-major contributions: contrib[t][k][d] (bf16 pairs packed in uint).
// Grid y=8: halves each block's serial dependent-load chain vs y=4.
__launch_bounds__(256)
__global__ void expert_contrib_kernel(const float* __restrict__ U,
                                      const ushort* __restrict__ rbf,
                                      const float* __restrict__ ws,
                                      uint* __restrict__ contrib) {
    const int e = blockIdx.x;
    const int tid = threadIdx.x;
    const int cnt = ((const int*)ws)[WS_CNT_I + e];
    if ((int)blockIdx.y >= cnt) return;

    float usc[16];
#pragma unroll
    for (int b = 0; b < 16; ++b) usc[b] = ws[WS_USCALE + (e << 4) + b];

    const float* Up = U + (size_t)e * (D * B);
    float u0[16], u1[16];
#pragma unroll
    for (int qd = 0; qd < 4; ++qd) {
        float4 a = *(const float4*)(Up + (size_t)(2 * tid) * B + qd * 4);
        float4 b4 = *(const float4*)(Up + (size_t)(2 * tid + 1) * B + qd * 4);
        u0[qd * 4 + 0] = a.x * usc[qd * 4 + 0];
        u0[qd * 4 + 1] = a.y * usc[qd * 4 + 1];
        u0[qd * 4 + 2] = a.z * usc[qd * 4 + 2];
        u0[qd * 4 + 3] = a.w * usc[qd * 4 + 3];
        u1[qd * 4 + 0] = b4.x * usc[qd * 4 + 0];
        u1[qd * 4 + 1] = b4.y * usc[qd * 4 + 1];
        u1[qd * 4 + 2] = b4.z * usc[qd * 4 + 2];
        u1[qd * 4 + 3] = b4.w * usc[qd * 4 + 3];
    }

    const int* ilist = (const int*)(ws + WS_LIST_F) + (e << 12);
    int i = blockIdx.y;
    int pk = (i < cnt) ? ilist[i] : 0;
    while (i < cnt) {
        const int t = pk >> 2, k = pk & 3;
        const ushort* rp = rbf + (size_t)t * NC + (e << 4);
        union { ushort u[16]; uint4 q[2]; } R;
        R.q[0] = *(const uint4*)(rp);
        R.q[1] = *(const uint4*)(rp + 8);
        const int inext = i + 8;
        if (inext < cnt) pk = ilist[inext];
        float acc0 = 0.0f, acc1 = 0.0f;
#pragma unroll
        for (int b = 0; b < 16; ++b) {
            const float wv = bf2f(R.u[b]);
            acc0 = fmaf(u0[b], wv, acc0);
            acc1 = fmaf(u1[b], wv, acc1);
        }
        contrib[(size_t)((t << 2) + k) * 256 + tid] =
            (uint)f2bf(acc0) | ((uint)f2bf(acc1) << 16);
        i = inext;
    }
}

// blocks 0..1023: out = x + sum_k contrib  ; block 1024: finalize scalars
__launch_bounds__(256)
__global__ void combine_kernel(const float* __restrict__ x,
                               const uint* __restrict__ contrib,
                               const float* __restrict__ ws,
                               float* __restrict__ out) {
    if (blockIdx.x == 1024) {               // finalize
        const int m = threadIdx.x;
        if (m >= 128) return;
        float e = ws[WS_EACC + m] * (1.0f / (float)NTOK);
        float c = ws[WS_CACC + m] * (1.0f / (float)NTOK);
        float s = e;
#pragma unroll
        for (int off = 32; off > 0; off >>= 1) s += __shfl_down(s, off);
        __shared__ float sh[2];
        if ((m & 63) == 0) sh[m >> 6] = s;
        __syncthreads();
        float total = sh[0] + sh[1];
        float total_energy = fmaxf(total, 1e-12f);
        out[OUT_EPE + m] = e;
        out[OUT_RE + m] = e / total_energy;
        out[OUT_SR + m] = c;
        if (m == 0) {
            out[OUT_TE] = total_energy;
            float inv_n2 = 1.0f / ((float)NC * (float)NC);
            float sqrtD = sqrtf((float)D);
            float vpen = ws[WS_VSUM] * inv_n2 * sqrtD;
            float upen = ws[WS_USUM] * inv_n2 * sqrtD;
            out[OUT_VPEN] = vpen;
            out[OUT_UPEN] = upen;
            out[OUT_AUX] = 0.01f * vpen - total_energy;
        }
        return;
    }

    const int gid = blockIdx.x * 256 + threadIdx.x;
    const int t = gid >> 6;
    const int dq = (gid & 63) << 3;
    const uint4* cp = (const uint4*)contrib;

    float s[8];
    float4 x0 = *(const float4*)(x + (size_t)t * D + dq);
    float4 x1 = *(const float4*)(x + (size_t)t * D + dq + 4);
    s[0] = x0.x; s[1] = x0.y; s[2] = x0.z; s[3] = x0.w;
    s[4] = x1.x; s[5] = x1.y; s[6] = x1.z; s[7] = x1.w;
#pragma unroll
    for (int k = 0; k < KSEL; ++k) {
        uint4 cvec = cp[(size_t)((t << 2) + k) * 64 + (dq >> 3)];
        uint cc[4] = {cvec.x, cvec.y, cvec.z, cvec.w};
#pragma unroll
        for (int j = 0; j < 4; ++j) {
            s[2 * j]     += bf2f((ushort)(cc[j] & 0xffffu));
            s[2 * j + 1] += bf2f((ushort)(cc[j] >> 16));
        }
    }
    float* op = out + (size_t)t * D + dq;
    *(float4*)(op)     = make_float4(s[0], s[1], s[2], s[3]);
    *(float4*)(op + 4) = make_float4(s[4], s[5], s[6], s[7]);
}

extern "C" void kernel_launch(void* const* d_in, const int* in_sizes, int n_in,
                              void* d_out, int out_size, void* d_ws, size_t ws_size,
                              hipStream_t stream) {
    const float* x  = (const float*)d_in[0];
    const float* V  = (const float*)d_in[1];
    const float* U  = (const float*)d_in[2];
    const float* us = (const float*)d_in[3];
    float* out = (float*)d_out;
    float* ws  = (float*)d_ws;

    ushort* xh  = (ushort*)(ws + WS_XH_F);
    ushort* xl  = (ushort*)(ws + WS_XL_F);
    ushort* vht = (ushort*)(ws + WS_VHT_F);
    ushort* vlt = (ushort*)(ws + WS_VLT_F);
    ushort* uht = (ushort*)(ws + WS_UHT_F);
    ushort* rbf = (ushort*)(ws + WS_RBF_F);
    uint* contrib = (uint*)(ws + WS_XH_F);   // reuses xh..ult after mfma_fused

    prep_kernel<<<1570, 256, 0, stream>>>(x, V, U, us, xh, xl, vht, vlt, uht, ws);
    mfma_fused<<<784, 256, 0, stream>>>(xh, xl, vht, vlt, uht, ws, rbf);
    topk_kernel<<<NTOK / 4, 256, 0, stream>>>(ws);
    listbuild_kernel<<<M, 256, 0, stream>>>(ws);
    expert_contrib_kernel<<<dim3(128, 8), 256, 0, stream>>>(U, rbf, ws, contrib);
    combine_kernel<<<1025, 256, 0, stream>>>(x, contrib, ws, out);
}